// Round 1
// baseline (2613.906 us; speedup 1.0000x reference)
//
#include <hip/hip_runtime.h>
#include <cstdint>
#include <cstddef>

#define B_ 4
#define S_ 1024
#define H_ 1024
#define NH_ 16
#define DK_ 64
#define DF_ 4096
#define L_ 4
#define V_ 32000

typedef __attribute__((ext_vector_type(8))) __bf16 bf16x8;
typedef __attribute__((ext_vector_type(4))) float f32x4;

__device__ __forceinline__ unsigned short f2b(float f) {
  unsigned u = __float_as_uint(f);
  u += 0x7FFFu + ((u >> 16) & 1u);   // round-to-nearest-even
  return (unsigned short)(u >> 16);
}

__device__ __forceinline__ void gload_lds16(const void* g, void* l) {
  __builtin_amdgcn_global_load_lds(
      (__attribute__((address_space(1))) void*)g,
      (__attribute__((address_space(3))) void*)l, 16, 0, 0);
}

// ---------------- embed: x = emb[ids] * sqrt(H), f32 + bf16 copies ----------
__global__ __launch_bounds__(256) void embed_k(const int* __restrict__ ids,
    const float* __restrict__ emb, float* __restrict__ x,
    unsigned short* __restrict__ xb)
{
  int tok = blockIdx.x, tid = threadIdx.x;
  int id = ids[tok];
  float4 v = ((const float4*)(emb + (size_t)id * H_))[tid];
  v.x *= 32.f; v.y *= 32.f; v.z *= 32.f; v.w *= 32.f;
  ((float4*)(x + (size_t)tok * H_))[tid] = v;
  ushort4 u; u.x = f2b(v.x); u.y = f2b(v.y); u.z = f2b(v.z); u.w = f2b(v.w);
  ((ushort4*)(xb + (size_t)tok * H_))[tid] = u;
}

// ---------------- transpose + convert: W (K,N) f32 -> WT (N,K) bf16 ---------
__global__ __launch_bounds__(256) void transpose_cvt(const float* __restrict__ W,
    unsigned short* __restrict__ WT, int K, int N)
{
  __shared__ float t[32][33];
  int n0 = blockIdx.x * 32, k0 = blockIdx.y * 32;
  int c = threadIdx.x & 31, r0 = threadIdx.x >> 5;
#pragma unroll
  for (int i = 0; i < 4; i++) {
    int r = r0 + i * 8;
    t[r][c] = W[(size_t)(k0 + r) * N + n0 + c];
  }
  __syncthreads();
#pragma unroll
  for (int i = 0; i < 4; i++) {
    int r = r0 + i * 8;
    WT[(size_t)(n0 + r) * K + k0 + c] = f2b(t[c][r]);
  }
}

// ---------------- concat bq|bk|bv per layer --------------------------------
__global__ __launch_bounds__(256) void concat_bias_k(const float* __restrict__ bq,
    const float* __restrict__ bk, const float* __restrict__ bv,
    float* __restrict__ out)
{
  int i = blockIdx.x * 256 + threadIdx.x;   // 0 .. L*3072-1
  int l = i / 3072, j = i - l * 3072;
  float v;
  if (j < 1024)       v = bq[l * 1024 + j];
  else if (j < 2048)  v = bk[l * 1024 + j - 1024];
  else                v = bv[l * 1024 + j - 2048];
  out[i] = v;
}

// ---------------- fused residual-add + layernorm ---------------------------
__global__ __launch_bounds__(256) void ln_k(const float* xin,
    const float* __restrict__ delta, const float* __restrict__ g,
    const float* __restrict__ bta, float* xout, unsigned short* __restrict__ xbout)
{
  int tok = blockIdx.x, tid = threadIdx.x;
  float4 a = ((const float4*)(xin + (size_t)tok * H_))[tid];
  float4 d = ((const float4*)(delta + (size_t)tok * H_))[tid];
  a.x += d.x; a.y += d.y; a.z += d.z; a.w += d.w;
  float s = a.x + a.y + a.z + a.w;
  float ss = a.x * a.x + a.y * a.y + a.z * a.z + a.w * a.w;
#pragma unroll
  for (int off = 32; off > 0; off >>= 1) {
    s += __shfl_down(s, off);
    ss += __shfl_down(ss, off);
  }
  __shared__ float red[8];
  if ((tid & 63) == 0) { red[tid >> 6] = s; red[4 + (tid >> 6)] = ss; }
  __syncthreads();
  float tot = red[0] + red[1] + red[2] + red[3];
  float tot2 = red[4] + red[5] + red[6] + red[7];
  float mu = tot * (1.f / H_);
  float var = tot2 * (1.f / H_) - mu * mu;
  float rs = rsqrtf(var + 1e-5f);
  float4 gv = ((const float4*)g)[tid];
  float4 bv = ((const float4*)bta)[tid];
  float4 y;
  y.x = (a.x - mu) * rs * gv.x + bv.x;
  y.y = (a.y - mu) * rs * gv.y + bv.y;
  y.z = (a.z - mu) * rs * gv.z + bv.z;
  y.w = (a.w - mu) * rs * gv.w + bv.w;
  ((float4*)(xout + (size_t)tok * H_))[tid] = y;
  ushort4 u; u.x = f2b(y.x); u.y = f2b(y.y); u.z = f2b(y.z); u.w = f2b(y.w);
  ((ushort4*)(xbout + (size_t)tok * H_))[tid] = u;
}

// ---------------- bf16 MFMA GEMM: C = A(MxK) @ BT(NxK)^T + bias ------------
// EPI 0: f32 -> Cf        EPI 2: gelu -> bf16 Cb
// EPI 3: QKV scatter (Cb=q, Ck=k, Cv=v^T)   EPI 4: logits w/ start_pos mask
template <int EPI>
__global__ __launch_bounds__(256) void gemm_bf16(
    const unsigned short* __restrict__ A, const unsigned short* __restrict__ BT,
    const float* __restrict__ bias, float* __restrict__ Cf,
    unsigned short* __restrict__ Cb, unsigned short* __restrict__ Ck,
    unsigned short* __restrict__ Cv, const int* __restrict__ spp,
    int M, int N, int K)
{
  __shared__ __align__(16) unsigned short As[128 * 32];
  __shared__ __align__(16) unsigned short Bs[128 * 32];
  int tid = threadIdx.x;
  int lane = tid & 63, w = tid >> 6;
  int lane15 = lane & 15, quad = lane >> 4;
  int wrow = w >> 1, wcol = w & 1;
  int n0 = blockIdx.x * 128, m0 = blockIdx.y * 128;

  f32x4 acc[4][4];
#pragma unroll
  for (int i = 0; i < 4; i++)
#pragma unroll
    for (int j = 0; j < 4; j++) acc[i][j] = (f32x4){0.f, 0.f, 0.f, 0.f};

  for (int k0 = 0; k0 < K; k0 += 32) {
    __syncthreads();
#pragma unroll
    for (int i = 0; i < 2; i++) {
      int c = tid + i * 256;               // 512 chunks of 16B per tile
      gload_lds16(A + (size_t)(m0 + (c >> 2)) * K + k0 + (c & 3) * 8, &As[c * 8]);
      gload_lds16(BT + (size_t)(n0 + (c >> 2)) * K + k0 + (c & 3) * 8, &Bs[c * 8]);
    }
    __syncthreads();
    bf16x8 af[4], bfm[4];
#pragma unroll
    for (int t = 0; t < 4; t++)
      af[t] = *(const bf16x8*)&As[(wrow * 64 + t * 16 + lane15) * 32 + quad * 8];
#pragma unroll
    for (int t = 0; t < 4; t++)
      bfm[t] = *(const bf16x8*)&Bs[(wcol * 64 + t * 16 + lane15) * 32 + quad * 8];
#pragma unroll
    for (int i = 0; i < 4; i++)
#pragma unroll
      for (int j = 0; j < 4; j++)
        acc[i][j] = __builtin_amdgcn_mfma_f32_16x16x32_bf16(af[i], bfm[j], acc[i][j], 0, 0, 0);
  }

#pragma unroll
  for (int i = 0; i < 4; i++) {
#pragma unroll
    for (int j = 0; j < 4; j++) {
      int n = n0 + wcol * 64 + j * 16 + lane15;
      float bv = bias[n];
#pragma unroll
      for (int r = 0; r < 4; r++) {
        int m = m0 + wrow * 64 + i * 16 + quad * 4 + r;
        float val = acc[i][j][r] + bv;
        if constexpr (EPI == 0) {
          Cf[(size_t)m * N + n] = val;
        } else if constexpr (EPI == 2) {
          val = 0.5f * val * (1.f + erff(val * 0.70710678118654752f));
          Cb[(size_t)m * N + n] = f2b(val);
        } else if constexpr (EPI == 3) {
          int bb = m >> 10, sTok = m & 1023;
          int seg = n >> 10, nl = n & 1023;
          int hh = nl >> 6, dd = nl & 63;
          if (seg == 2) {
            Cv[(((size_t)bb * NH_ + hh) * DK_ + dd) * S_ + sTok] = f2b(val);
          } else {
            size_t o = (((size_t)bb * NH_ + hh) * S_ + sTok) * DK_ + dd;
            (seg == 0 ? Cb : Ck)[o] = f2b(val);
          }
        } else if constexpr (EPI == 4) {
          int bb = m >> 10, sTok = m & 1023;
          Cf[(size_t)m * N + n] = (sTok >= spp[bb]) ? val : 0.f;
        }
      }
    }
  }
}

// ---------------- flash attention (alibi + custom mask, online softmax) -----
__global__ __launch_bounds__(256) void flash_k(
    const unsigned short* __restrict__ qb, const unsigned short* __restrict__ kb,
    const unsigned short* __restrict__ vT, const int* __restrict__ spp,
    unsigned short* __restrict__ attnx)
{
  __shared__ __align__(16) unsigned short Ks[64 * 64];
  __shared__ __align__(16) unsigned short Vs[64 * 64];
  __shared__ __align__(16) unsigned short Pb[4 * 16 * 64];
  int tid = threadIdx.x;
  int w = tid >> 6, lane = tid & 63, lane15 = lane & 15, quad = lane >> 4;
  int qchunk = blockIdx.x, bh = blockIdx.y;
  int b = bh >> 4, h = bh & 15;
  int sp = spp[b];
  float slope = exp2f(-0.5f * (float)(h + 1));
  const unsigned short* qg = qb + (size_t)bh * S_ * DK_;
  const unsigned short* kg = kb + (size_t)bh * S_ * DK_;
  const unsigned short* vg = vT + (size_t)bh * DK_ * S_;
  int qrow0 = qchunk * 64 + w * 16;

  bf16x8 qf0 = *(const bf16x8*)(qg + (size_t)(qrow0 + lane15) * DK_ + quad * 8);
  bf16x8 qf1 = *(const bf16x8*)(qg + (size_t)(qrow0 + lane15) * DK_ + quad * 8 + 32);

  f32x4 o[4];
  float mrun[4], lrun[4];
#pragma unroll
  for (int r = 0; r < 4; r++) { mrun[r] = -__builtin_inff(); lrun[r] = 0.f; }
#pragma unroll
  for (int dt = 0; dt < 4; dt++) o[dt] = (f32x4){0.f, 0.f, 0.f, 0.f};

  // rows with s_q >= 128 > max(start_pos) are strictly causal
  int nkt = (qchunk >= 2) ? (qchunk + 1) : 16;

  for (int kt = 0; kt < nkt; kt++) {
    __syncthreads();                                  // prev iter LDS reads done
#pragma unroll
    for (int i = 0; i < 2; i++) {
      int c = tid + i * 256;
      int row = c >> 3, c8 = c & 7;
      gload_lds16(kg + (size_t)(kt * 64 + row) * DK_ + c8 * 8, &Ks[c * 8]);
      gload_lds16(vg + (size_t)row * S_ + kt * 64 + c8 * 8, &Vs[c * 8]);
    }
    __syncthreads();                                  // staging drained

    float sc[4][4];                                   // [nt][reg]
#pragma unroll
    for (int nt = 0; nt < 4; nt++) {
      bf16x8 kf0 = *(const bf16x8*)&Ks[(nt * 16 + lane15) * 64 + quad * 8];
      bf16x8 kf1 = *(const bf16x8*)&Ks[(nt * 16 + lane15) * 64 + quad * 8 + 32];
      f32x4 z = (f32x4){0.f, 0.f, 0.f, 0.f};
      z = __builtin_amdgcn_mfma_f32_16x16x32_bf16(qf0, kf0, z, 0, 0, 0);
      z = __builtin_amdgcn_mfma_f32_16x16x32_bf16(qf1, kf1, z, 0, 0, 0);
      int sk = kt * 64 + nt * 16 + lane15;
#pragma unroll
      for (int r = 0; r < 4; r++) {
        int sq = qrow0 + quad * 4 + r;
        float v = z[r] * 0.125f + slope * (float)(sk - sp);
        bool vis = (sk <= sq) || (sk < sp) || (sq < sp);
        sc[nt][r] = vis ? v : -1e9f;
      }
    }

    float alpha[4];
#pragma unroll
    for (int r = 0; r < 4; r++) {
      float m = fmaxf(fmaxf(sc[0][r], sc[1][r]), fmaxf(sc[2][r], sc[3][r]));
#pragma unroll
      for (int off = 8; off; off >>= 1) m = fmaxf(m, __shfl_xor(m, off));
      float mnew = fmaxf(mrun[r], m);
      alpha[r] = expf(mrun[r] - mnew);
      mrun[r] = mnew;
      float ps = 0.f;
#pragma unroll
      for (int nt = 0; nt < 4; nt++) {
        float p = expf(sc[nt][r] - mnew);
        sc[nt][r] = p;
        ps += p;
      }
#pragma unroll
      for (int off = 8; off; off >>= 1) ps += __shfl_xor(ps, off);
      lrun[r] = lrun[r] * alpha[r] + ps;
    }
#pragma unroll
    for (int dt = 0; dt < 4; dt++)
#pragma unroll
      for (int r = 0; r < 4; r++) o[dt][r] *= alpha[r];

    // P: C-layout -> A-layout via LDS
#pragma unroll
    for (int nt = 0; nt < 4; nt++)
#pragma unroll
      for (int r = 0; r < 4; r++)
        Pb[w * 1024 + (quad * 4 + r) * 64 + nt * 16 + lane15] = f2b(sc[nt][r]);
    __syncthreads();

    bf16x8 pf0 = *(const bf16x8*)&Pb[w * 1024 + lane15 * 64 + quad * 8];
    bf16x8 pf1 = *(const bf16x8*)&Pb[w * 1024 + lane15 * 64 + quad * 8 + 32];
#pragma unroll
    for (int dt = 0; dt < 4; dt++) {
      bf16x8 vf0 = *(const bf16x8*)&Vs[(dt * 16 + lane15) * 64 + quad * 8];
      bf16x8 vf1 = *(const bf16x8*)&Vs[(dt * 16 + lane15) * 64 + quad * 8 + 32];
      o[dt] = __builtin_amdgcn_mfma_f32_16x16x32_bf16(pf0, vf0, o[dt], 0, 0, 0);
      o[dt] = __builtin_amdgcn_mfma_f32_16x16x32_bf16(pf1, vf1, o[dt], 0, 0, 0);
    }
  }

#pragma unroll
  for (int dt = 0; dt < 4; dt++)
#pragma unroll
    for (int r = 0; r < 4; r++) {
      int sq = qrow0 + quad * 4 + r;
      float ov = o[dt][r] / lrun[r];
      attnx[((size_t)(b * S_ + sq)) * H_ + h * DK_ + dt * 16 + lane15] = f2b(ov);
    }
}

// ---------------------------------------------------------------------------
extern "C" void kernel_launch(void* const* d_in, const int* in_sizes, int n_in,
                              void* d_out, int out_size, void* d_ws, size_t ws_size,
                              hipStream_t stream)
{
  const int* ids  = (const int*)d_in[0];
  const int* sp   = (const int*)d_in[1];
  const float* emb = (const float*)d_in[2];
  const float* Wq = (const float*)d_in[3];
  const float* bq = (const float*)d_in[4];
  const float* Wk = (const float*)d_in[5];
  const float* bk = (const float*)d_in[6];
  const float* Wv = (const float*)d_in[7];
  const float* bvv = (const float*)d_in[8];
  const float* Wo = (const float*)d_in[9];
  const float* bo = (const float*)d_in[10];
  const float* ln1g = (const float*)d_in[11];
  const float* ln1b = (const float*)d_in[12];
  const float* ln2g = (const float*)d_in[13];
  const float* ln2b = (const float*)d_in[14];
  const float* W1 = (const float*)d_in[15];
  const float* b1 = (const float*)d_in[16];
  const float* W2 = (const float*)d_in[17];
  const float* b2 = (const float*)d_in[18];
  const float* Wf = (const float*)d_in[19];
  const float* bf = (const float*)d_in[20];
  float* out = (float*)d_out;

  char* ws = (char*)d_ws;
  size_t off = 0;
  auto carve = [&](size_t bytes) -> void* {
    void* p = ws + off;
    off += (bytes + 255) & ~(size_t)255;
    return p;
  };
  float* x            = (float*)carve((size_t)4096 * 1024 * 4);
  unsigned short* xb  = (unsigned short*)carve((size_t)4096 * 1024 * 2);
  float* tmp          = (float*)carve((size_t)4096 * 1024 * 4);
  unsigned short* h1  = (unsigned short*)carve((size_t)4096 * 4096 * 2);
  unsigned short* attnx = (unsigned short*)carve((size_t)4096 * 1024 * 2);
  unsigned short* qbuf  = (unsigned short*)carve((size_t)64 * 1024 * 64 * 2);
  unsigned short* kbuf  = (unsigned short*)carve((size_t)64 * 1024 * 64 * 2);
  unsigned short* vbuf  = (unsigned short*)carve((size_t)64 * 1024 * 64 * 2);
  unsigned short* WqkvT = (unsigned short*)carve((size_t)3072 * 1024 * 2);
  unsigned short* WoT   = (unsigned short*)carve((size_t)1024 * 1024 * 2);
  unsigned short* W1T   = (unsigned short*)carve((size_t)4096 * 1024 * 2);
  unsigned short* W2T   = (unsigned short*)carve((size_t)1024 * 4096 * 2);
  unsigned short* WfT   = (unsigned short*)carve((size_t)32000 * 1024 * 2);
  float* bqkv           = (float*)carve((size_t)4 * 3072 * 4);

  concat_bias_k<<<48, 256, 0, stream>>>(bq, bk, bvv, bqkv);
  embed_k<<<4096, 256, 0, stream>>>(ids, emb, x, xb);
  transpose_cvt<<<dim3(1000, 32), 256, 0, stream>>>(Wf, WfT, 1024, 32000);

  for (int l = 0; l < 4; l++) {
    transpose_cvt<<<dim3(32, 32), 256, 0, stream>>>(Wq + (size_t)l * 1024 * 1024, WqkvT, 1024, 1024);
    transpose_cvt<<<dim3(32, 32), 256, 0, stream>>>(Wk + (size_t)l * 1024 * 1024, WqkvT + (size_t)1024 * 1024, 1024, 1024);
    transpose_cvt<<<dim3(32, 32), 256, 0, stream>>>(Wv + (size_t)l * 1024 * 1024, WqkvT + (size_t)2048 * 1024, 1024, 1024);
    transpose_cvt<<<dim3(32, 32), 256, 0, stream>>>(Wo + (size_t)l * 1024 * 1024, WoT, 1024, 1024);
    transpose_cvt<<<dim3(128, 32), 256, 0, stream>>>(W1 + (size_t)l * 1024 * 4096, W1T, 1024, 4096);
    transpose_cvt<<<dim3(32, 128), 256, 0, stream>>>(W2 + (size_t)l * 4096 * 1024, W2T, 4096, 1024);

    gemm_bf16<3><<<dim3(24, 32), 256, 0, stream>>>(xb, WqkvT, bqkv + l * 3072,
        nullptr, qbuf, kbuf, vbuf, nullptr, 4096, 3072, 1024);
    flash_k<<<dim3(16, 64), 256, 0, stream>>>(qbuf, kbuf, vbuf, sp, attnx);
    gemm_bf16<0><<<dim3(8, 32), 256, 0, stream>>>(attnx, WoT, bo + l * 1024,
        tmp, nullptr, nullptr, nullptr, nullptr, 4096, 1024, 1024);
    ln_k<<<4096, 256, 0, stream>>>(x, tmp, ln1g + l * 1024, ln1b + l * 1024, x, xb);
    gemm_bf16<2><<<dim3(32, 32), 256, 0, stream>>>(xb, W1T, b1 + l * 4096,
        nullptr, h1, nullptr, nullptr, nullptr, 4096, 4096, 1024);
    gemm_bf16<0><<<dim3(8, 32), 256, 0, stream>>>(h1, W2T, b2 + l * 1024,
        tmp, nullptr, nullptr, nullptr, nullptr, 4096, 1024, 4096);
    ln_k<<<4096, 256, 0, stream>>>(x, tmp, ln2g + l * 1024, ln2b + l * 1024, x, xb);
  }

  gemm_bf16<4><<<dim3(250, 32), 256, 0, stream>>>(xb, WfT, bf,
      out, nullptr, nullptr, nullptr, sp, 4096, 32000, 1024);
}